// Round 3
// baseline (286.599 us; speedup 1.0000x reference)
//
#include <hip/hip_runtime.h>
#include <hip/hip_fp16.h>
#include <math.h>

#define NNODES 40000
#define NEDGES 640000
#define NGRAPH 64
#define CAP 96                 // slots per dst bucket (max random-degree ~45)
constexpr float LN_EPS = 1e-5f;

// R1 LESSON (measured): multi-edge-per-instruction (divergent per-lane addresses)
// collapsed throughput 60->235us. SGPR-base (readlane) + contiguous lane offset,
// ONE edge per VMEM instruction, is the mandatory fast path.
// R2 LESSON (measured): 2 nodes/wave alternating 8-batches gave only -12% (60->53us)
// because the schedule drains vmcnt to 0 every iteration (sawtooth). D64==D128 time
// => cost is per-VMEM-slot round trips, not bytes. R3: 4 chains, never-drain pipeline.

// ================= butterfly wave reduction (all lanes get result) =================
__device__ __forceinline__ float bf_sum(float v) {
    #pragma unroll
    for (int o = 32; o > 0; o >>= 1) v += __shfl_xor(v, o);
    return v;
}
__device__ __forceinline__ void bf_sum4(float& a, float& b, float& c, float& d) {
    #pragma unroll
    for (int o = 32; o > 0; o >>= 1) {
        a += __shfl_xor(a, o);
        b += __shfl_xor(b, o);
        c += __shfl_xor(c, o);
        d += __shfl_xor(d, o);
    }
}

// ================= prep: zero cnt/sums + transpose W1,W2 (one kernel) =================
__global__ void prep(const float* __restrict__ W1, const float* __restrict__ W2,
                     float* __restrict__ Wt1, float* __restrict__ Wt2,
                     int* __restrict__ cnt, float* __restrict__ sums) {
    int t = blockIdx.x * 256 + threadIdx.x;
    if (t < NNODES) cnt[t] = 0;
    if (t < 128 * 128) { int o = t / 128, i = t % 128; Wt1[i * 128 + o] = W1[t]; }
    if (t < 64 * 128)  { int o = t / 128, i = t % 128; Wt2[i * 64 + o] = W2[t]; }
    if (t < NGRAPH * 64) sums[t] = 0.f;
}

// ================= binning (random edges only; self-loops analytic) =================
__global__ void bin_edges(const int* __restrict__ ei, int E,
                          int* __restrict__ cnt, unsigned short* __restrict__ ssrc) {
    int e = blockIdx.x * blockDim.x + threadIdx.x;
    if (e >= E) return;
    int s = ei[e], d = ei[E + e];
    int pos = atomicAdd(cnt + d, 1);
    if (pos < CAP) ssrc[d * CAP + pos] = (unsigned short)s;
}

// ================= GEMM + scores: register-tiled 4ch x NPT nodes per thread =========
template<int DIN, int DOUT, int NPT>
__global__ __launch_bounds__(256) void gemm_scores(
        const float* __restrict__ X, const float* __restrict__ Wt,
        const float* __restrict__ asrc, const float* __restrict__ adst,
        __half* __restrict__ H, float* __restrict__ S, float* __restrict__ Dv) {
    constexpr int CHG = DOUT / 4;        // threads along channel dim
    constexpr int NG  = 256 / CHG;       // node-groups per block
    constexpr int NPB = NG * NPT;        // nodes per block
    static_assert(NPB == 64, "NPB must be 64");
    __shared__ float xs[DIN][NPB];
    __shared__ float ps[NG][NPT][2];
    const int base = blockIdx.x * NPB;
    const int tid = threadIdx.x;
    #pragma unroll
    for (int i4 = tid; i4 < NPB * DIN / 4; i4 += 256) {
        const int nd = i4 % NPB, c4 = i4 / NPB;
        float4 v = *(const float4*)(X + (size_t)(base + nd) * DIN + 4 * c4);
        xs[4 * c4 + 0][nd] = v.x;
        xs[4 * c4 + 1][nd] = v.y;
        xs[4 * c4 + 2][nd] = v.z;
        xs[4 * c4 + 3][nd] = v.w;
    }
    __syncthreads();
    const int cg = tid % CHG, ng = tid / CHG;
    const int c0 = 4 * cg, n0 = ng * NPT;
    float acc[NPT][4];
    #pragma unroll
    for (int n = 0; n < NPT; ++n)
        #pragma unroll
        for (int k = 0; k < 4; ++k) acc[n][k] = 0.f;
    #pragma unroll 2
    for (int i = 0; i < DIN; ++i) {
        const float4 w = *(const float4*)(Wt + i * DOUT + c0);
        #pragma unroll
        for (int n4 = 0; n4 < NPT / 4; ++n4) {
            const float4 xv = *(const float4*)&xs[i][n0 + 4 * n4];
            const float xf[4] = {xv.x, xv.y, xv.z, xv.w};
            #pragma unroll
            for (int j = 0; j < 4; ++j) {
                const int n = 4 * n4 + j;
                acc[n][0] += xf[j] * w.x; acc[n][1] += xf[j] * w.y;
                acc[n][2] += xf[j] * w.z; acc[n][3] += xf[j] * w.w;
            }
        }
    }
    #pragma unroll
    for (int n = 0; n < NPT; ++n) {
        __half2 p01 = __floats2half2_rn(acc[n][0], acc[n][1]);
        __half2 p23 = __floats2half2_rn(acc[n][2], acc[n][3]);
        __half2* hp = (__half2*)(H + (size_t)(base + n0 + n) * DOUT + c0);
        hp[0] = p01; hp[1] = p23;
    }
    const float4 asf = *(const float4*)(asrc + c0);
    const float4 adf = *(const float4*)(adst + c0);
    float sp[NPT], dp[NPT];
    #pragma unroll
    for (int n = 0; n < NPT; ++n) {
        sp[n] = acc[n][0]*asf.x + acc[n][1]*asf.y + acc[n][2]*asf.z + acc[n][3]*asf.w;
        dp[n] = acc[n][0]*adf.x + acc[n][1]*adf.y + acc[n][2]*adf.z + acc[n][3]*adf.w;
    }
    #pragma unroll
    for (int o = CHG / 2; o > 0; o >>= 1) {
        #pragma unroll
        for (int n = 0; n < NPT; ++n) {
            sp[n] += __shfl_xor(sp[n], o);
            dp[n] += __shfl_xor(dp[n], o);
        }
    }
    if (cg == 0) {
        #pragma unroll
        for (int n = 0; n < NPT; ++n) { ps[ng][n][0] = sp[n]; ps[ng][n][1] = dp[n]; }
    }
    __syncthreads();
    if (tid < NPB) {
        S[base + tid]  = ps[tid / NPT][tid % NPT][0];
        Dv[base + tid] = ps[tid / NPT][tid % NPT][1];
    }
}

// ================= generic single-node aggregation (any deg; rare big-deg path) =====
template<int D>
__device__ __forceinline__ void aggr_one_generic(
        const int node, const int deg, const int lane,
        const unsigned short* __restrict__ ssrc, const float* __restrict__ S,
        const float dsc, const __half* __restrict__ H,
        float& acc0, float& acc1, float& z) {
    constexpr int VPL = D / 64;
    float zz = 0.f;
    const int r0 = node * CAP;
    for (int bse = 0; bse < deg; bse += 64) {
        const int n = min(64, deg - bse);
        int s = 0; float a = 0.f;
        if (lane < n) {
            s = ssrc[r0 + bse + lane];
            float t = S[s] + dsc;
            t = t > 0.f ? t : 0.2f * t;
            a = __expf(t);
        }
        zz += bf_sum(a);
        const int abits = __float_as_int(a);
        for (int j = 0; j < n; ++j) {
            const int sj = __builtin_amdgcn_readlane(s, j);
            const float aj = __int_as_float(__builtin_amdgcn_readlane(abits, j));
            const __half* hp = H + (size_t)sj * D;
            if (VPL == 1) {
                acc0 += aj * __half2float(hp[lane]);
            } else {
                const float2 f = __half22float2(*(const __half2*)(hp + 2 * lane));
                acc0 += aj * f.x; acc1 += aj * f.y;
            }
        }
    }
    z = zz;
}

// ================= epilogue: self-loop + normalize + bias + ReLU + LN + store =======
template<int D, int POOL>
__device__ __forceinline__ void finish_node(
        const int node, const int lane,
        float acc0, float acc1, float z, const float aself, const float2 selfF,
        const float* __restrict__ b, const float* __restrict__ gam,
        const float* __restrict__ bet,
        float* __restrict__ out, const int* __restrict__ batch,
        float* __restrict__ sums) {
    constexpr int VPL = D / 64;
    acc0 += aself * selfF.x;
    if (VPL == 2) acc1 += aself * selfF.y;
    z += aself;
    const float zinv = 1.0f / z;
    float vv[VPL], lsum = 0.f;
    vv[0] = acc0;
    if (VPL == 2) vv[1] = acc1;
    #pragma unroll
    for (int k = 0; k < VPL; ++k) {
        const int ch = VPL * lane + k;
        vv[k] = fmaxf(vv[k] * zinv + b[ch], 0.f);
        lsum += vv[k];
    }
    const float mu = bf_sum(lsum) / D;
    float q = 0.f;
    #pragma unroll
    for (int k = 0; k < VPL; ++k) { vv[k] -= mu; q += vv[k] * vv[k]; }
    const float rstd = rsqrtf(bf_sum(q) / D + LN_EPS);
    #pragma unroll
    for (int k = 0; k < VPL; ++k) {
        const int ch = VPL * lane + k;
        vv[k] = gam[ch] * vv[k] * rstd + bet[ch];
    }
    if (POOL) {
        const int bg = batch[node];                 // uniform per wave
        atomicAdd(&sums[bg * D + lane], vv[0]);     // POOL only used with D=64
    } else {
        if (VPL == 1) out[(size_t)node * D + lane] = vv[0];
        else *(float2*)(out + (size_t)node * D + 2 * lane) = make_float2(vv[0], vv[1]);
    }
}

// ================= fused GAT: FOUR nodes/wave, never-draining load pipeline =========
template<int D, int POOL>
__global__ __launch_bounds__(256) void gat_aggr(
        const int* __restrict__ cnt, const unsigned short* __restrict__ ssrc,
        const float* __restrict__ S, const float* __restrict__ Dv,
        const __half* __restrict__ H,
        const float* __restrict__ b, const float* __restrict__ gam,
        const float* __restrict__ bet,
        float* __restrict__ out, const int* __restrict__ batch,
        float* __restrict__ sums) {
    constexpr int VPL = D / 64;
    const int lane = threadIdx.x & 63;
    const int wv   = threadIdx.x >> 6;
    const int nbase = blockIdx.x * 16 + wv * 4;     // 4 nodes per wave
    const int node0 = nbase + 0, node1 = nbase + 1;
    const int node2 = nbase + 2, node3 = nbase + 3;

    const int deg0 = min(__builtin_amdgcn_readfirstlane(cnt[node0]), CAP);
    const int deg1 = min(__builtin_amdgcn_readfirstlane(cnt[node1]), CAP);
    const int deg2 = min(__builtin_amdgcn_readfirstlane(cnt[node2]), CAP);
    const int deg3 = min(__builtin_amdgcn_readfirstlane(cnt[node3]), CAP);
    const float dsc0 = Dv[node0], dsc1 = Dv[node1];
    const float dsc2 = Dv[node2], dsc3 = Dv[node3];

    // self-loop score terms
    float ts0 = S[node0] + dsc0; ts0 = ts0 > 0.f ? ts0 : 0.2f * ts0;
    float ts1 = S[node1] + dsc1; ts1 = ts1 > 0.f ? ts1 : 0.2f * ts1;
    float ts2 = S[node2] + dsc2; ts2 = ts2 > 0.f ? ts2 : 0.2f * ts2;
    float ts3 = S[node3] + dsc3; ts3 = ts3 > 0.f ? ts3 : 0.2f * ts3;
    const float as0 = __expf(ts0), as1 = __expf(ts1);
    const float as2 = __expf(ts2), as3 = __expf(ts3);

    float acc0_0 = 0.f, acc1_0 = 0.f, acc0_1 = 0.f, acc1_1 = 0.f;
    float acc0_2 = 0.f, acc1_2 = 0.f, acc0_3 = 0.f, acc1_3 = 0.f;
    float z0, z1, z2, z3;

    if (deg0 <= 64 && deg1 <= 64 && deg2 <= 64 && deg3 <= 64) {
        // ---- phase 1: 4 ssrc rows, 4 S gathers, all overlapped ----
        int s_0 = 0, s_1 = 0, s_2 = 0, s_3 = 0;
        if (lane < deg0) s_0 = ssrc[node0 * CAP + lane];
        if (lane < deg1) s_1 = ssrc[node1 * CAP + lane];
        if (lane < deg2) s_2 = ssrc[node2 * CAP + lane];
        if (lane < deg3) s_3 = ssrc[node3 * CAP + lane];
        float t0 = S[s_0] + dsc0, t1 = S[s_1] + dsc1;
        float t2 = S[s_2] + dsc2, t3 = S[s_3] + dsc3;
        t0 = t0 > 0.f ? t0 : 0.2f * t0;
        t1 = t1 > 0.f ? t1 : 0.2f * t1;
        t2 = t2 > 0.f ? t2 : 0.2f * t2;
        t3 = t3 > 0.f ? t3 : 0.2f * t3;
        float a0 = (lane < deg0) ? __expf(t0) : 0.f;
        float a1 = (lane < deg1) ? __expf(t1) : 0.f;
        float a2 = (lane < deg2) ? __expf(t2) : 0.f;
        float a3 = (lane < deg3) ? __expf(t3) : 0.f;
        z0 = a0; z1 = a1; z2 = a2; z3 = a3;
        bf_sum4(z0, z1, z2, z3);
        const int ab_0 = __float_as_int(a0), ab_1 = __float_as_int(a1);
        const int ab_2 = __float_as_int(a2), ab_3 = __float_as_int(a3);

        // ---- phase 2: rolling pipeline, >=16 loads always outstanding ----
        const int nb0 = (deg0 + 7) >> 3, nb1 = (deg1 + 7) >> 3;
        const int nb2 = (deg2 + 7) >> 3, nb3 = (deg3 + 7) >> 3;
        const int T = max(max(nb0, nb1), max(nb2, nb3));

        __half2 hv_0[8], hv_1[8], hv_2[8], hv_3[8];   // VPL==2 buffers
        __half  hs_0[8], hs_1[8], hs_2[8], hs_3[8];   // VPL==1 buffers

#define ISSUE(r, j) do {                                                        \
    _Pragma("unroll")                                                           \
    for (int u = 0; u < 8; ++u) {                                               \
        const int sj = __builtin_amdgcn_readlane(s_##r, 8 * (j) + u);           \
        const __half* hp = H + (size_t)sj * D;                                  \
        if (VPL == 1) hs_##r[u] = hp[lane];                                     \
        else          hv_##r[u] = *(const __half2*)(hp + 2 * lane);             \
    } } while (0)

#define COMPUTE(r, j) do {                                                      \
    _Pragma("unroll")                                                           \
    for (int u = 0; u < 8; ++u) {                                               \
        const float av =                                                        \
            __int_as_float(__builtin_amdgcn_readlane(ab_##r, 8 * (j) + u));     \
        if (VPL == 1) {                                                         \
            acc0_##r += av * __half2float(hs_##r[u]);                           \
        } else {                                                                \
            const float2 f = __half22float2(hv_##r[u]);                         \
            acc0_##r += av * f.x; acc1_##r += av * f.y;                         \
        }                                                                       \
    } } while (0)

        if (0 < nb0) ISSUE(0, 0);
        if (0 < nb1) ISSUE(1, 0);
        for (int j = 0; j < T; ++j) {
            if (j < nb2) ISSUE(2, j);
            if (j < nb0) COMPUTE(0, j);
            if (j < nb3) ISSUE(3, j);
            if (j < nb1) COMPUTE(1, j);
            if (j + 1 < nb0) ISSUE(0, j + 1);
            if (j < nb2) COMPUTE(2, j);
            if (j + 1 < nb1) ISSUE(1, j + 1);
            if (j < nb3) COMPUTE(3, j);
        }
#undef ISSUE
#undef COMPUTE
    } else {
        // ---- rare: some bucket >64 -> generic chunked path, sequential ----
        aggr_one_generic<D>(node0, deg0, lane, ssrc, S, dsc0, H, acc0_0, acc1_0, z0);
        aggr_one_generic<D>(node1, deg1, lane, ssrc, S, dsc1, H, acc0_1, acc1_1, z1);
        aggr_one_generic<D>(node2, deg2, lane, ssrc, S, dsc2, H, acc0_2, acc1_2, z2);
        aggr_one_generic<D>(node3, deg3, lane, ssrc, S, dsc3, H, acc0_3, acc1_3, z3);
    }

    // ---- self H rows (4 coalesced loads, issued together) ----
    float2 sf0, sf1, sf2, sf3;
    if (VPL == 1) {
        sf0 = make_float2(__half2float(H[(size_t)node0 * D + lane]), 0.f);
        sf1 = make_float2(__half2float(H[(size_t)node1 * D + lane]), 0.f);
        sf2 = make_float2(__half2float(H[(size_t)node2 * D + lane]), 0.f);
        sf3 = make_float2(__half2float(H[(size_t)node3 * D + lane]), 0.f);
    } else {
        sf0 = __half22float2(*(const __half2*)(H + (size_t)node0 * D + 2 * lane));
        sf1 = __half22float2(*(const __half2*)(H + (size_t)node1 * D + 2 * lane));
        sf2 = __half22float2(*(const __half2*)(H + (size_t)node2 * D + 2 * lane));
        sf3 = __half22float2(*(const __half2*)(H + (size_t)node3 * D + 2 * lane));
    }

    finish_node<D, POOL>(node0, lane, acc0_0, acc1_0, z0, as0, sf0, b, gam, bet, out, batch, sums);
    finish_node<D, POOL>(node1, lane, acc0_1, acc1_1, z1, as1, sf1, b, gam, bet, out, batch, sums);
    finish_node<D, POOL>(node2, lane, acc0_2, acc1_2, z2, as2, sf2, b, gam, bet, out, batch, sums);
    finish_node<D, POOL>(node3, lane, acc0_3, acc1_3, z3, as3, sf3, b, gam, bet, out, batch, sums);
}

// ================= head: mean (cnt via binary search on sorted batch) + 2 linears ====
__global__ void final_head(const float* __restrict__ sums, const int* __restrict__ batch,
                           const float* __restrict__ Wl, const float* __restrict__ bl,
                           const float* __restrict__ Wc, const float* __restrict__ bc,
                           float* __restrict__ out) {
    __shared__ float p[64];
    __shared__ float red[64];
    const int g = blockIdx.x, tid = threadIdx.x;
    int lo = 0, hi = NNODES;
    while (lo < hi) { int mid = (lo + hi) >> 1; if (batch[mid] < g) lo = mid + 1; else hi = mid; }
    int lo2 = lo, hi2 = NNODES;
    while (lo2 < hi2) { int mid = (lo2 + hi2) >> 1; if (batch[mid] < g + 1) lo2 = mid + 1; else hi2 = mid; }
    const float cnt = (float)(lo2 - lo);
    p[tid] = sums[g * 64 + tid] / fmaxf(cnt, 1.0f);
    __syncthreads();
    float t = bl[tid];
    #pragma unroll 8
    for (int k = 0; k < 64; ++k) t += Wl[tid * 64 + k] * p[k];
    red[tid] = Wc[tid] * t;
    __syncthreads();
    for (int s = 32; s > 0; s >>= 1) {
        if (tid < s) red[tid] += red[tid + s];
        __syncthreads();
    }
    if (tid == 0) out[g] = red[0] + bc[0];
}

extern "C" void kernel_launch(void* const* d_in, const int* in_sizes, int n_in,
                              void* d_out, int out_size, void* d_ws, size_t ws_size,
                              hipStream_t stream) {
    const int N = NNODES, E = NEDGES, G = NGRAPH;

    const float* x      = (const float*)d_in[0];
    const int*   ei     = (const int*)d_in[1];
    const int*   batch  = (const int*)d_in[2];
    const float* W1     = (const float*)d_in[3];
    const float* a1s    = (const float*)d_in[4];
    const float* a1d    = (const float*)d_in[5];
    const float* b1     = (const float*)d_in[6];
    const float* g1     = (const float*)d_in[7];
    const float* be1    = (const float*)d_in[8];
    const float* W2     = (const float*)d_in[9];
    const float* a2s    = (const float*)d_in[10];
    const float* a2d    = (const float*)d_in[11];
    const float* b2     = (const float*)d_in[12];
    const float* g2     = (const float*)d_in[13];
    const float* be2    = (const float*)d_in[14];
    const float* Wl     = (const float*)d_in[15];
    const float* bl     = (const float*)d_in[16];
    const float* Wc     = (const float*)d_in[17];
    const float* bc     = (const float*)d_in[18];

    // ---- workspace carve-up ----
    char* w = (char*)d_ws;
    __half* h1  = (__half*)w; w += (size_t)N * 128 * 2;   // fp16 H
    float* acc1 = (float*)w; w += (size_t)N * 128 * 4;
    float* S    = (float*)w; w += (size_t)N * 4;
    float* Dv   = (float*)w; w += (size_t)N * 4;
    int* cnt    = (int*)w;   w += (size_t)N * 4;
    unsigned short* ssrc = (unsigned short*)w; w += (size_t)N * CAP * 2;
    float* Wt1  = (float*)w; w += (size_t)128 * 128 * 4;
    float* Wt2  = (float*)w; w += (size_t)128 * 64 * 4;
    float* sums = (float*)w; w += (size_t)G * 64 * 4;
    __half* h2 = h1;

    const int TB = 256;
    const int gridN = (N + 255) / 256;

    // ---- prep (zero cnt/sums + W transposes) ----
    prep<<<gridN, 256, 0, stream>>>(W1, W2, Wt1, Wt2, cnt, sums);

    // ---- edge binning (random edges only; self-loops analytic) ----
    bin_edges<<<(E + TB - 1) / TB, TB, 0, stream>>>(ei, E, cnt, ssrc);

    // ---- layer 1 (128 -> 128) ----
    gemm_scores<128, 128, 8><<<N / 64, 256, 0, stream>>>(x, Wt1, a1s, a1d, h1, S, Dv);
    gat_aggr<128, 0><<<N / 16, 256, 0, stream>>>(cnt, ssrc, S, Dv, h1, b1, g1, be1,
                                                 acc1, nullptr, nullptr);

    // ---- layer 2 (128 -> 64), pool fused ----
    gemm_scores<128, 64, 4><<<N / 64, 256, 0, stream>>>(acc1, Wt2, a2s, a2d, h2, S, Dv);
    gat_aggr<64, 1><<<N / 16, 256, 0, stream>>>(cnt, ssrc, S, Dv, h2, b2, g2, be2,
                                                nullptr, batch, sums);

    // ---- head ----
    final_head<<<G, 64, 0, stream>>>(sums, batch, Wl, bl, Wc, bc, (float*)d_out);
}

// Round 4
// 245.585 us; speedup vs baseline: 1.1670x; 1.1670x over previous
//
#include <hip/hip_runtime.h>
#include <hip/hip_fp16.h>
#include <math.h>

#define NNODES 40000
#define NEDGES 640000
#define NGRAPH 64
#define CAP 96                 // slots per dst bucket (max random-degree ~45)
constexpr float LN_EPS = 1e-5f;

// R1 LESSON (measured): multi-edge-per-instruction (divergent per-lane addresses)
// collapsed throughput 60->235us. SGPR-base (readlane) + contiguous lane offset,
// ONE edge per VMEM instruction, is the mandatory fast path.
// R2 LESSON (measured): 2 nodes/wave interleaved = 53us (-12% vs R0's 60).
// R3 LESSON (measured): 4 chains/wave deep pipeline REGRESSED (68us, occupancy
// 56->40%): longer waves + max-degree imbalance. Aggr is at its scattered-request
// service wall at the R2 point; fixed at R2 structure below.
// R4: attack the fp32 GEMMs (MfmaUtil was 0 everywhere) with fp16 MFMA.

typedef _Float16 v8h __attribute__((ext_vector_type(8)));
typedef float    v4f __attribute__((ext_vector_type(4)));

// ================= butterfly wave reduction (all lanes get result) =================
__device__ __forceinline__ float bf_sum(float v) {
    #pragma unroll
    for (int o = 32; o > 0; o >>= 1) v += __shfl_xor(v, o);
    return v;
}

// ================= prep: zero cnt/sums + build MFMA B-fragments for W1,W2 ==========
// B-frag layout for v_mfma_f32_16x16x32_f16: lane l = g*16+lc holds B[k][n] with
// n = lc, k = ks*32 + g*8 + j (j=0..7). Same (g,j)->k mapping used for A frags in
// the GEMM, so the MFMA dot-product is correct independent of HW's internal K perm.
__global__ void prep(const float* __restrict__ W1, const float* __restrict__ W2,
                     _Float16* __restrict__ Bf1, _Float16* __restrict__ Bf2,
                     int* __restrict__ cnt, float* __restrict__ sums) {
    int t = blockIdx.x * 256 + threadIdx.x;
    if (t < NNODES) cnt[t] = 0;
    if (t < 128 * 128) {
        const int o = t >> 7, k = t & 127;             // W1[o][k], o=out ch, k=in ch
        const int nt = o >> 4, lc = o & 15;
        const int ks = k >> 5, g = (k >> 3) & 3, j = k & 7;
        Bf1[(size_t)(((nt * 4 + ks) * 64 + g * 16 + lc) * 8 + j)] = (_Float16)W1[t];
    }
    if (t < 64 * 128) {
        const int o = t >> 7, k = t & 127;
        const int nt = o >> 4, lc = o & 15;
        const int ks = k >> 5, g = (k >> 3) & 3, j = k & 7;
        Bf2[(size_t)(((nt * 4 + ks) * 64 + g * 16 + lc) * 8 + j)] = (_Float16)W2[t];
    }
    if (t < NGRAPH * 64) sums[t] = 0.f;
}

// ================= binning (random edges only; self-loops analytic) =================
__global__ void bin_edges(const int* __restrict__ ei, int E,
                          int* __restrict__ cnt, unsigned short* __restrict__ ssrc) {
    int e = blockIdx.x * blockDim.x + threadIdx.x;
    if (e >= E) return;
    int s = ei[e], d = ei[E + e];
    int pos = atomicAdd(cnt + d, 1);
    if (pos < CAP) ssrc[d * CAP + pos] = (unsigned short)s;
}

// ================= GEMM + scores via MFMA (fp16 in, fp32 accum) ====================
// Per block: 64 nodes, 4 waves; per wave a 16-node M-tile x DOUT, K=128 in 4 ksteps.
// A frag: lane l=g*16+lc holds X[nb+lc][ks*32+g*8+j] cast to fp16 (no LDS needed).
// D frag: col = lane&15 (out ch), row = (lane>>4)*4 + r (node) [m89-verified].
template<int DOUT>
__global__ __launch_bounds__(256) void gemm_scores_mfma(
        const float* __restrict__ X, const _Float16* __restrict__ Bfrag,
        const float* __restrict__ asrc, const float* __restrict__ adst,
        __half* __restrict__ H, float* __restrict__ S, float* __restrict__ Dv) {
    constexpr int NT = DOUT / 16;
    const int lane = threadIdx.x & 63;
    const int wv   = threadIdx.x >> 6;
    const int nb   = blockIdx.x * 64 + wv * 16;      // wave's 16-node tile
    const int lc = lane & 15, g = lane >> 4;

    // ---- A fragments: 4 ksteps, fp32->fp16 on the fly ----
    v8h a[4];
    const float* xr = X + (size_t)(nb + lc) * 128 + g * 8;
    #pragma unroll
    for (int ks = 0; ks < 4; ++ks) {
        const float4 lo = *(const float4*)(xr + ks * 32);
        const float4 hi = *(const float4*)(xr + ks * 32 + 4);
        v8h av;
        av[0] = (_Float16)lo.x; av[1] = (_Float16)lo.y;
        av[2] = (_Float16)lo.z; av[3] = (_Float16)lo.w;
        av[4] = (_Float16)hi.x; av[5] = (_Float16)hi.y;
        av[6] = (_Float16)hi.z; av[7] = (_Float16)hi.w;
        a[ks] = av;
    }

    v4f acc[NT];
    #pragma unroll
    for (int nt = 0; nt < NT; ++nt) acc[nt] = (v4f){0.f, 0.f, 0.f, 0.f};

    #pragma unroll
    for (int ks = 0; ks < 4; ++ks) {
        #pragma unroll
        for (int nt = 0; nt < NT; ++nt) {       // independent accs -> MFMA ILP
            const v8h bv = *(const v8h*)(Bfrag + (size_t)(((nt * 4 + ks) * 64 + lane) * 8));
            acc[nt] = __builtin_amdgcn_mfma_f32_16x16x32_f16(a[ks], bv, acc[nt], 0, 0, 0);
        }
    }

    // ---- H store (fp16) + score partials ----
    float sp[4] = {0.f, 0.f, 0.f, 0.f}, dp[4] = {0.f, 0.f, 0.f, 0.f};
    #pragma unroll
    for (int nt = 0; nt < NT; ++nt) {
        const float as_ = asrc[nt * 16 + lc];
        const float ad_ = adst[nt * 16 + lc];
        #pragma unroll
        for (int r = 0; r < 4; ++r) {
            const float hv = acc[nt][r];
            H[(size_t)(nb + g * 4 + r) * DOUT + nt * 16 + lc] = __float2half_rn(hv);
            sp[r] += hv * as_;
            dp[r] += hv * ad_;
        }
    }
    // reduce over the 16 out-channel lanes (stays within 16-lane groups)
    #pragma unroll
    for (int o = 8; o > 0; o >>= 1) {
        #pragma unroll
        for (int r = 0; r < 4; ++r) {
            sp[r] += __shfl_xor(sp[r], o);
            dp[r] += __shfl_xor(dp[r], o);
        }
    }
    #pragma unroll
    for (int r = 0; r < 4; ++r) {
        if (lc == r) {
            S[nb + g * 4 + r]  = sp[r];
            Dv[nb + g * 4 + r] = dp[r];
        }
    }
}

// ================= generic single-node aggregation (any deg; rare big-deg path) =====
template<int D>
__device__ __forceinline__ void aggr_one_generic(
        const int node, const int deg, const int lane,
        const unsigned short* __restrict__ ssrc, const float* __restrict__ S,
        const float dsc, const __half* __restrict__ H,
        float& acc0, float& acc1, float& z) {
    constexpr int VPL = D / 64;
    float zz = 0.f;
    const int r0 = node * CAP;
    for (int bse = 0; bse < deg; bse += 64) {
        const int n = min(64, deg - bse);
        int s = 0; float a = 0.f;
        if (lane < n) {
            s = ssrc[r0 + bse + lane];
            float t = S[s] + dsc;
            t = t > 0.f ? t : 0.2f * t;
            a = __expf(t);
        }
        zz += bf_sum(a);
        const int abits = __float_as_int(a);
        for (int j = 0; j < n; ++j) {
            const int sj = __builtin_amdgcn_readlane(s, j);
            const float aj = __int_as_float(__builtin_amdgcn_readlane(abits, j));
            const __half* hp = H + (size_t)sj * D;
            if (VPL == 1) {
                acc0 += aj * __half2float(hp[lane]);
            } else {
                const float2 f = __half22float2(*(const __half2*)(hp + 2 * lane));
                acc0 += aj * f.x; acc1 += aj * f.y;
            }
        }
    }
    z = zz;
}

// ================= epilogue: self-loop + normalize + bias + ReLU + LN + store =======
template<int D, int POOL>
__device__ __forceinline__ void finish_node(
        const int node, const int lane,
        float acc0, float acc1, float z, const float aself, const float2 selfF,
        const float* __restrict__ b, const float* __restrict__ gam,
        const float* __restrict__ bet,
        float* __restrict__ out, const int* __restrict__ batch,
        float* __restrict__ sums) {
    constexpr int VPL = D / 64;
    acc0 += aself * selfF.x;
    if (VPL == 2) acc1 += aself * selfF.y;
    z += aself;
    const float zinv = 1.0f / z;
    float vv[VPL], lsum = 0.f;
    vv[0] = acc0;
    if (VPL == 2) vv[1] = acc1;
    #pragma unroll
    for (int k = 0; k < VPL; ++k) {
        const int ch = VPL * lane + k;
        vv[k] = fmaxf(vv[k] * zinv + b[ch], 0.f);
        lsum += vv[k];
    }
    const float mu = bf_sum(lsum) / D;
    float q = 0.f;
    #pragma unroll
    for (int k = 0; k < VPL; ++k) { vv[k] -= mu; q += vv[k] * vv[k]; }
    const float rstd = rsqrtf(bf_sum(q) / D + LN_EPS);
    #pragma unroll
    for (int k = 0; k < VPL; ++k) {
        const int ch = VPL * lane + k;
        vv[k] = gam[ch] * vv[k] * rstd + bet[ch];
    }
    if (POOL) {
        const int bg = batch[node];                 // uniform per wave
        atomicAdd(&sums[bg * D + lane], vv[0]);     // POOL only used with D=64
    } else {
        if (VPL == 1) out[(size_t)node * D + lane] = vv[0];
        else *(float2*)(out + (size_t)node * D + 2 * lane) = make_float2(vv[0], vv[1]);
    }
}

// ================= fused GAT: TWO nodes per wave, interleaved chains (R2) ===========
template<int D, int POOL>
__global__ __launch_bounds__(256) void gat_aggr(
        const int* __restrict__ cnt, const unsigned short* __restrict__ ssrc,
        const float* __restrict__ S, const float* __restrict__ Dv,
        const __half* __restrict__ H,
        const float* __restrict__ b, const float* __restrict__ gam,
        const float* __restrict__ bet,
        float* __restrict__ out, const int* __restrict__ batch,
        float* __restrict__ sums) {
    constexpr int VPL = D / 64;
    const int lane = threadIdx.x & 63;
    const int wv   = threadIdx.x >> 6;
    const int nodeA = blockIdx.x * 8 + wv * 2;      // 2 nodes per wave
    const int nodeB = nodeA + 1;

    const int degA = min(__builtin_amdgcn_readfirstlane(cnt[nodeA]), CAP);
    const int degB = min(__builtin_amdgcn_readfirstlane(cnt[nodeB]), CAP);
    const float dscA = Dv[nodeA], dscB = Dv[nodeB];

    // self-loop score terms
    float tsA = S[nodeA] + dscA; tsA = tsA > 0.f ? tsA : 0.2f * tsA;
    float tsB = S[nodeB] + dscB; tsB = tsB > 0.f ? tsB : 0.2f * tsB;
    const float aselfA = __expf(tsA);
    const float aselfB = __expf(tsB);

    // self H rows (coalesced, issued early so they're resident by the epilogue)
    float2 selfFA, selfFB;
    if (VPL == 1) {
        selfFA = make_float2(__half2float(H[(size_t)nodeA * D + lane]), 0.f);
        selfFB = make_float2(__half2float(H[(size_t)nodeB * D + lane]), 0.f);
    } else {
        selfFA = __half22float2(*(const __half2*)(H + (size_t)nodeA * D + 2 * lane));
        selfFB = __half22float2(*(const __half2*)(H + (size_t)nodeB * D + 2 * lane));
    }

    float accA0 = 0.f, accA1 = 0.f, accB0 = 0.f, accB1 = 0.f;
    float zA, zB;

    if (degA <= 64 && degB <= 64) {
        // ---- phase 1: both ssrc rows, then both S gathers (4 loads overlapped) ----
        int sA = 0, sB = 0;
        if (lane < degA) sA = ssrc[nodeA * CAP + lane];
        if (lane < degB) sB = ssrc[nodeB * CAP + lane];
        float tA = S[sA] + dscA;                    // idle lanes read S[0]: harmless
        float tB = S[sB] + dscB;
        tA = tA > 0.f ? tA : 0.2f * tA;
        tB = tB > 0.f ? tB : 0.2f * tB;
        const float aA = (lane < degA) ? __expf(tA) : 0.f;
        const float aB = (lane < degB) ? __expf(tB) : 0.f;
        zA = bf_sum(aA);
        zB = bf_sum(aB);
        const int abA = __float_as_int(aA), abB = __float_as_int(aB);

        // ---- phase 2: alternate 8-load batches of A and B (16 loads in flight) ----
        const int nmA = (degA + 7) & ~7;
        const int nmB = (degB + 7) & ~7;
        const int nmax = max(nmA, nmB);
        for (int j = 0; j < nmax; j += 8) {
            const bool doA = j < nmA, doB = j < nmB;   // wave-uniform
            float afA[8], afB[8];
            __half2 hvA[8], hvB[8];
            __half hsA[8], hsB[8];
            if (doA) {
                #pragma unroll
                for (int u = 0; u < 8; ++u) {
                    const int sj = __builtin_amdgcn_readlane(sA, j + u);
                    afA[u] = __int_as_float(__builtin_amdgcn_readlane(abA, j + u));
                    const __half* hp = H + (size_t)sj * D;
                    if (VPL == 1) hsA[u] = hp[lane];
                    else          hvA[u] = *(const __half2*)(hp + 2 * lane);
                }
            }
            if (doB) {
                #pragma unroll
                for (int u = 0; u < 8; ++u) {
                    const int sj = __builtin_amdgcn_readlane(sB, j + u);
                    afB[u] = __int_as_float(__builtin_amdgcn_readlane(abB, j + u));
                    const __half* hp = H + (size_t)sj * D;
                    if (VPL == 1) hsB[u] = hp[lane];
                    else          hvB[u] = *(const __half2*)(hp + 2 * lane);
                }
            }
            if (doA) {
                #pragma unroll
                for (int u = 0; u < 8; ++u) {
                    if (VPL == 1) {
                        accA0 += afA[u] * __half2float(hsA[u]);
                    } else {
                        accA0 += afA[u] * __half2float(__low2half(hvA[u]));
                        accA1 += afA[u] * __half2float(__high2half(hvA[u]));
                    }
                }
            }
            if (doB) {
                #pragma unroll
                for (int u = 0; u < 8; ++u) {
                    if (VPL == 1) {
                        accB0 += afB[u] * __half2float(hsB[u]);
                    } else {
                        accB0 += afB[u] * __half2float(__low2half(hvB[u]));
                        accB1 += afB[u] * __half2float(__high2half(hvB[u]));
                    }
                }
            }
        }
    } else {
        // ---- rare: at least one big bucket -> generic chunked path, sequential ----
        aggr_one_generic<D>(nodeA, degA, lane, ssrc, S, dscA, H, accA0, accA1, zA);
        aggr_one_generic<D>(nodeB, degB, lane, ssrc, S, dscB, H, accB0, accB1, zB);
    }

    finish_node<D, POOL>(nodeA, lane, accA0, accA1, zA, aselfA, selfFA,
                         b, gam, bet, out, batch, sums);
    finish_node<D, POOL>(nodeB, lane, accB0, accB1, zB, aselfB, selfFB,
                         b, gam, bet, out, batch, sums);
}

// ================= head: mean (cnt via binary search on sorted batch) + 2 linears ====
__global__ void final_head(const float* __restrict__ sums, const int* __restrict__ batch,
                           const float* __restrict__ Wl, const float* __restrict__ bl,
                           const float* __restrict__ Wc, const float* __restrict__ bc,
                           float* __restrict__ out) {
    __shared__ float p[64];
    __shared__ float red[64];
    const int g = blockIdx.x, tid = threadIdx.x;
    int lo = 0, hi = NNODES;
    while (lo < hi) { int mid = (lo + hi) >> 1; if (batch[mid] < g) lo = mid + 1; else hi = mid; }
    int lo2 = lo, hi2 = NNODES;
    while (lo2 < hi2) { int mid = (lo2 + hi2) >> 1; if (batch[mid] < g + 1) lo2 = mid + 1; else hi2 = mid; }
    const float cnt = (float)(lo2 - lo);
    p[tid] = sums[g * 64 + tid] / fmaxf(cnt, 1.0f);
    __syncthreads();
    float t = bl[tid];
    #pragma unroll 8
    for (int k = 0; k < 64; ++k) t += Wl[tid * 64 + k] * p[k];
    red[tid] = Wc[tid] * t;
    __syncthreads();
    for (int s = 32; s > 0; s >>= 1) {
        if (tid < s) red[tid] += red[tid + s];
        __syncthreads();
    }
    if (tid == 0) out[g] = red[0] + bc[0];
}

extern "C" void kernel_launch(void* const* d_in, const int* in_sizes, int n_in,
                              void* d_out, int out_size, void* d_ws, size_t ws_size,
                              hipStream_t stream) {
    const int N = NNODES, E = NEDGES, G = NGRAPH;

    const float* x      = (const float*)d_in[0];
    const int*   ei     = (const int*)d_in[1];
    const int*   batch  = (const int*)d_in[2];
    const float* W1     = (const float*)d_in[3];
    const float* a1s    = (const float*)d_in[4];
    const float* a1d    = (const float*)d_in[5];
    const float* b1     = (const float*)d_in[6];
    const float* g1     = (const float*)d_in[7];
    const float* be1    = (const float*)d_in[8];
    const float* W2     = (const float*)d_in[9];
    const float* a2s    = (const float*)d_in[10];
    const float* a2d    = (const float*)d_in[11];
    const float* b2     = (const float*)d_in[12];
    const float* g2     = (const float*)d_in[13];
    const float* be2    = (const float*)d_in[14];
    const float* Wl     = (const float*)d_in[15];
    const float* bl     = (const float*)d_in[16];
    const float* Wc     = (const float*)d_in[17];
    const float* bc     = (const float*)d_in[18];

    // ---- workspace carve-up ----
    char* w = (char*)d_ws;
    __half* h1  = (__half*)w; w += (size_t)N * 128 * 2;   // fp16 H
    float* acc1 = (float*)w; w += (size_t)N * 128 * 4;
    float* S    = (float*)w; w += (size_t)N * 4;
    float* Dv   = (float*)w; w += (size_t)N * 4;
    int* cnt    = (int*)w;   w += (size_t)N * 4;
    unsigned short* ssrc = (unsigned short*)w; w += (size_t)N * CAP * 2;
    _Float16* Bf1 = (_Float16*)w; w += (size_t)128 * 128 * 2;   // MFMA B-frags W1
    _Float16* Bf2 = (_Float16*)w; w += (size_t)64 * 128 * 2;    // MFMA B-frags W2
    float* sums = (float*)w; w += (size_t)G * 64 * 4;
    __half* h2 = h1;

    const int TB = 256;
    const int gridN = (N + 255) / 256;

    // ---- prep (zero cnt/sums + build W1/W2 MFMA fragments) ----
    prep<<<gridN, 256, 0, stream>>>(W1, W2, Bf1, Bf2, cnt, sums);

    // ---- edge binning (random edges only; self-loops analytic) ----
    bin_edges<<<(E + TB - 1) / TB, TB, 0, stream>>>(ei, E, cnt, ssrc);

    // ---- layer 1 (128 -> 128) ----
    gemm_scores_mfma<128><<<N / 64, 256, 0, stream>>>(x, Bf1, a1s, a1d, h1, S, Dv);
    gat_aggr<128, 0><<<N / 8, 256, 0, stream>>>(cnt, ssrc, S, Dv, h1, b1, g1, be1,
                                                acc1, nullptr, nullptr);

    // ---- layer 2 (128 -> 64), pool fused ----
    gemm_scores_mfma<64><<<N / 64, 256, 0, stream>>>(acc1, Bf2, a2s, a2d, h2, S, Dv);
    gat_aggr<64, 1><<<N / 8, 256, 0, stream>>>(cnt, ssrc, S, Dv, h2, b2, g2, be2,
                                               nullptr, batch, sums);

    // ---- head ----
    final_head<<<G, 64, 0, stream>>>(sums, batch, Wl, bl, Wc, bc, (float*)d_out);
}